// Round 2
// baseline (7288.828 us; speedup 1.0000x reference)
//
#include <hip/hip_runtime.h>

typedef unsigned short u16;
typedef unsigned int u32;
typedef __bf16 bf16x8 __attribute__((ext_vector_type(8)));
typedef float f32x4 __attribute__((ext_vector_type(4)));

union Pack8 { uint4 u; u16 s[8]; bf16x8 b; };

__device__ __forceinline__ float bf2f(u16 u) {
    union { u32 i; float f; } v; v.i = ((u32)u) << 16; return v.f;
}
__device__ __forceinline__ u16 f2bf(float f) {
    u32 x = __float_as_uint(f);
    u32 r = x + 0x7fffu + ((x >> 16) & 1u);
    return (u16)(r >> 16);
}
__device__ __forceinline__ float sigf(float x) { return 1.f / (1.f + __expf(-x)); }

// ---------------------------------------------------------------------------
// Generic bf16-input GEMM, fp32 accum: C[M,N] = A[M,K]*B[K,N] (+fp32 bias).
// flags bit0 = bf16 out (else fp32), bit1 = relu. Batched on z:
// A += z*sA, B += (z&zmaskB)*sB, C += z*sC, bias += z*sBias.
// Block 256 thr = 4 waves; tile 64x64, BK=32. M%64==0, N%64==0, K%32==0.
// MFMA 16x16x32 bf16; layouts (m89-verified): A[m=lane&15][k=(lane>>4)*8+j],
// B[k=(lane>>4)*8+j][n=lane&15], C[row=(lane>>4)*4+r][col=lane&15].
// ---------------------------------------------------------------------------
__global__ __launch_bounds__(256) void gemm_bf16(
    const u16* __restrict__ A, long sA, int lda,
    const u16* __restrict__ B, long sB, int ldb, int zmaskB,
    void* __restrict__ Cv, long sC, int ldc,
    const float* __restrict__ bias, long sBias,
    int K, int flags)
{
    const int z = blockIdx.z;
    A += (size_t)z * sA;
    B += (size_t)(z & zmaskB) * sB;
    const int bm = blockIdx.y * 64, bn = blockIdx.x * 64;
    __shared__ __align__(16) u16 As[64 * 40];   // As[row][k], pad 32->40
    __shared__ __align__(16) u16 Bs[64 * 40];   // Bs[n][k] (transposed)
    const int tid = threadIdx.x;
    const int w = tid >> 6, l = tid & 63;
    const int lr = l & 15, lq = l >> 4;
    f32x4 acc[4] = {};
    const int arow = tid >> 2, acol = (tid & 3) << 3;
    const int bnn = tid & 63, bkg = tid >> 6;

    for (int k0 = 0; k0 < K; k0 += 32) {
        uint4 av = *(const uint4*)(A + (size_t)(bm + arow) * lda + (k0 + acol));
        *(uint4*)(As + arow * 40 + acol) = av;
        Pack8 pb;
        const u16* bp = B + (size_t)(k0 + bkg * 8) * ldb + (bn + bnn);
        #pragma unroll
        for (int j = 0; j < 8; ++j) pb.s[j] = bp[(size_t)j * ldb];
        *(uint4*)(Bs + bnn * 40 + bkg * 8) = pb.u;
        __syncthreads();

        bf16x8 af = ((const Pack8*)(As + (w * 16 + lr) * 40 + lq * 8))->b;
        #pragma unroll
        for (int nt = 0; nt < 4; ++nt) {
            bf16x8 bf = ((const Pack8*)(Bs + (nt * 16 + lr) * 40 + lq * 8))->b;
            acc[nt] = __builtin_amdgcn_mfma_f32_16x16x32_bf16(af, bf, acc[nt], 0, 0, 0);
        }
        __syncthreads();
    }

    const int outbf = flags & 1, relu = flags & 2;
    u16* Cb = (u16*)Cv + (size_t)z * sC;
    float* Cf = (float*)Cv + (size_t)z * sC;
    #pragma unroll
    for (int nt = 0; nt < 4; ++nt) {
        int col = bn + nt * 16 + lr;
        float bv = bias ? bias[(size_t)z * sBias + col] : 0.f;
        #pragma unroll
        for (int r = 0; r < 4; ++r) {
            int row = bm + w * 16 + lq * 4 + r;
            float v = acc[nt][r] + bv;
            if (relu) v = fmaxf(v, 0.f);
            if (outbf) Cb[(size_t)row * ldc + col] = f2bf(v);
            else       Cf[(size_t)row * ldc + col] = v;
        }
    }
}

// ---------------------------------------------------------------------------
__global__ __launch_bounds__(256) void cvt_f2b(const float* __restrict__ s,
                                               u16* __restrict__ d, int n8)
{
    int i = blockIdx.x * 256 + threadIdx.x;
    if (i >= n8) return;
    float4 a = ((const float4*)s)[2 * i], b = ((const float4*)s)[2 * i + 1];
    Pack8 p;
    p.s[0] = f2bf(a.x); p.s[1] = f2bf(a.y); p.s[2] = f2bf(a.z); p.s[3] = f2bf(a.w);
    p.s[4] = f2bf(b.x); p.s[5] = f2bf(b.y); p.s[6] = f2bf(b.z); p.s[7] = f2bf(b.w);
    ((uint4*)d)[i] = p.u;
}

__global__ __launch_bounds__(256) void copy_f32(const float4* __restrict__ s,
                                                float4* __restrict__ d, int n4)
{
    int i = blockIdx.x * 256 + threadIdx.x;
    if (i < n4) d[i] = s[i];
}

__global__ __launch_bounds__(256) void zero16(uint4* d, int n16)
{
    int i = blockIdx.x * 256 + threadIdx.x;
    if (i < n16) d[i] = make_uint4(0, 0, 0, 0);
}

// gather fp32 embedding rows -> bf16; grid (B*S, 3), block 64
__global__ void embed_kernel(const int* __restrict__ sd, const int* __restrict__ td,
                             const int* __restrict__ rd,
                             const float* __restrict__ semb, const float* __restrict__ temb,
                             u16* __restrict__ src_e, u16* __restrict__ rat_e,
                             u16* __restrict__ tgt_e)
{
    int pos = blockIdx.x, which = blockIdx.y;
    const int* idxp = (which == 0) ? sd : (which == 1) ? rd : td;
    const float* emb = (which == 2) ? temb : semb;
    u16* dst = (which == 0) ? src_e : (which == 1) ? rat_e : tgt_e;
    int row = idxp[pos];
    const float4* s = (const float4*)(emb + (size_t)row * 512);
    int t = threadIdx.x;
    float4 a = s[2 * t], b = s[2 * t + 1];
    Pack8 p;
    p.s[0] = f2bf(a.x); p.s[1] = f2bf(a.y); p.s[2] = f2bf(a.z); p.s[3] = f2bf(a.w);
    p.s[4] = f2bf(b.x); p.s[5] = f2bf(b.y); p.s[6] = f2bf(b.z); p.s[7] = f2bf(b.w);
    ((uint4*)(dst + (size_t)pos * 512))[t] = p.u;
}

// encoder cell for 4 LSTMs: grid (128, 4). z: 0=src_f 1=src_b 2=rat_f 3=rat_b
__global__ __launch_bounds__(256) void enc_cell(
    const float* __restrict__ hg, const u16* __restrict__ xg,
    float* __restrict__ h, float* __restrict__ c, u16* __restrict__ hbf,
    u16* __restrict__ enc_out, u16* __restrict__ enc_out_r, int t)
{
    int lstm = blockIdx.y;
    int i = blockIdx.x * 256 + threadIdx.x;      // 0..32767
    int b = i >> 9, j = i & 511;
    int bwd = lstm & 1;
    int sx = bwd ? (63 - t) : t;
    const float* hgp = hg + ((size_t)lstm * 64 + b) * 2048;
    const u16* xgp = xg + ((size_t)lstm * 4096 + (size_t)b * 64 + sx) * 2048;
    float gi = hgp[j]        + bf2f(xgp[j]);
    float gf = hgp[512 + j]  + bf2f(xgp[512 + j]);
    float gg = hgp[1024 + j] + bf2f(xgp[1024 + j]);
    float go = hgp[1536 + j] + bf2f(xgp[1536 + j]);
    size_t hi = (size_t)lstm * 32768 + (size_t)b * 512 + j;
    float cv = sigf(gf) * c[hi] + sigf(gi) * tanhf(gg);
    float hv = sigf(go) * tanhf(cv);
    c[hi] = cv; h[hi] = hv; hbf[hi] = f2bf(hv);
    u16* eo = (lstm < 2) ? enc_out : enc_out_r;
    eo[((size_t)b * 64 + sx) * 1024 + (bwd ? 512 : 0) + j] = f2bf(hv);
}

__global__ __launch_bounds__(256) void init_dec(
    const float* __restrict__ h0, const float* __restrict__ c0,
    const u16* __restrict__ h0bf, float* __restrict__ dh, float* __restrict__ dc,
    u16* __restrict__ dhbf, u16* __restrict__ x_cat, const u16* __restrict__ tgt_e)
{
    int i = blockIdx.x * 256 + threadIdx.x;      // 0..32767
    int b = i >> 9, j = i & 511;
    dh[i] = h0[i]; dc[i] = c0[i];
    u16 v = h0bf[i];
    dhbf[i] = v;
    x_cat[(size_t)b * 3072 + 2560 + j] = v;
    x_cat[(size_t)b * 3072 + j] = tgt_e[((size_t)b * 64) * 512 + j];
}

__global__ __launch_bounds__(256) void score_kernel(
    const u16* __restrict__ encW1, const float* __restrict__ hW1,
    const float* __restrict__ W2, const float* __restrict__ b2,
    float* __restrict__ scores)
{
    int item = blockIdx.x * 4 + (threadIdx.x >> 6);
    int l = threadIdx.x & 63;
    int att = item >> 12, bs = item & 4095, b = bs >> 6;
    const u16* ep = encW1 + ((size_t)att * 4096 + bs) * 1536;
    const float* hp = hW1 + (size_t)b * 1536;
    float e = 0.f;
    for (int idx = l; idx < 1536; idx += 64) {
        float v = fmaxf(bf2f(ep[idx]) + hp[idx], 0.f);
        e += v * W2[idx];
    }
    #pragma unroll
    for (int off = 32; off; off >>= 1) e += __shfl_down(e, off, 64);
    if (l == 0) scores[item] = e + b2[0];
}

__global__ __launch_bounds__(256) void attn_out(
    const float* __restrict__ scores, const u16* __restrict__ enc_all,
    u16* __restrict__ x_cat, u16* __restrict__ Abuf, int t)
{
    int b = blockIdx.x, att = blockIdx.y;
    __shared__ float wgt[64];
    int tid = threadIdx.x;
    const float* sp = scores + (size_t)att * 4096 + (size_t)b * 64;
    if (tid < 64) {
        float x = sp[tid];
        float m = x;
        #pragma unroll
        for (int off = 32; off; off >>= 1) m = fmaxf(m, __shfl_xor(m, off, 64));
        float e = __expf(x - m);
        float s = e;
        #pragma unroll
        for (int off = 32; off; off >>= 1) s += __shfl_xor(s, off, 64);
        wgt[tid] = e / s;
    }
    __syncthreads();
    const u16* enc = enc_all + (size_t)att * 4194304 + (size_t)b * 65536;
    for (int n = tid; n < 1024; n += 256) {
        float acc = 0.f;
        for (int s = 0; s < 64; ++s) acc += wgt[s] * bf2f(enc[(size_t)s * 1024 + n]);
        u16 bv = f2bf(acc);
        x_cat[(size_t)b * 3072 + 512 + (size_t)att * 1024 + n] = bv;
        Abuf[(((size_t)att * 64 + b) * 32 + t) * 1024 + n] = bv;
    }
}

__global__ __launch_bounds__(256) void dec_cell(
    const float* __restrict__ gates, float* __restrict__ h, float* __restrict__ c,
    u16* __restrict__ hbf, u16* __restrict__ x_cat, u16* __restrict__ Dbuf,
    const u16* __restrict__ tgt_e, int t)
{
    int i = blockIdx.x * 256 + threadIdx.x;      // 0..32767
    int b = i >> 9, j = i & 511;
    const float* gp = gates + (size_t)b * 2048;
    float gi = gp[j], gf = gp[512 + j], gg = gp[1024 + j], go = gp[1536 + j];
    float cv = sigf(gf) * c[i] + sigf(gi) * tanhf(gg);
    float hv = sigf(go) * tanhf(cv);
    c[i] = cv; h[i] = hv;
    u16 hb = f2bf(hv);
    hbf[i] = hb;
    x_cat[(size_t)b * 3072 + 2560 + j] = hb;
    Dbuf[((size_t)b * 32 + t) * 512 + j] = hb;
    x_cat[(size_t)b * 3072 + j] = tgt_e[((size_t)b * 64 + (t + 1)) * 512 + j];
}

__global__ __launch_bounds__(256) void build_ci(
    const u16* __restrict__ tgt_e, const u16* __restrict__ Abuf,
    const float* __restrict__ graph, const u16* __restrict__ Dbuf,
    u16* __restrict__ ci)
{
    int row = blockIdx.x;
    int b = row >> 6, t = row & 63;
    u16* cp = ci + (size_t)row * 3328;
    for (int n = threadIdx.x; n < 3328; n += 256) {
        u16 v;
        if (n < 512)       v = tgt_e[(size_t)row * 512 + n];
        else if (n < 1536) v = (t < 32) ? Abuf[((size_t)b * 32 + t) * 1024 + (n - 512)] : (u16)0;
        else if (n < 2560) v = (t < 32) ? Abuf[2097152 + ((size_t)b * 32 + t) * 1024 + (n - 1536)] : (u16)0;
        else if (n < 2816) v = f2bf(graph[(size_t)b * 256 + (n - 2560)]);
        else               v = (t < 32) ? Dbuf[((size_t)b * 32 + t) * 512 + (n - 2816)] : (u16)0;
        cp[n] = v;
    }
}

// ---------------------------------------------------------------------------
extern "C" void kernel_launch(void* const* d_in, const int* in_sizes, int n_in,
                              void* d_out, int out_size, void* d_ws, size_t ws_size,
                              hipStream_t stream)
{
    (void)in_sizes; (void)n_in; (void)out_size; (void)ws_size;

    const int* source_data = (const int*)d_in[0];
    const int* target_data = (const int*)d_in[1];
    const int* rationales  = (const int*)d_in[2];
    const float* graph_embs = (const float*)d_in[3];
    const float* src_emb = (const float*)d_in[4];
    const float* tgt_emb = (const float*)d_in[5];
    const float* enc_Wih_f = (const float*)d_in[6];
    const float* enc_Whh_f = (const float*)d_in[7];
    const float* enc_b_f   = (const float*)d_in[8];
    const float* enc_Wih_b = (const float*)d_in[9];
    const float* enc_Whh_b = (const float*)d_in[10];
    const float* enc_b_b   = (const float*)d_in[11];
    const float* dec_Wih = (const float*)d_in[12];
    const float* dec_Whh = (const float*)d_in[13];
    const float* dec_b   = (const float*)d_in[14];
    const float* att_W1 = (const float*)d_in[15];
    const float* att_b1 = (const float*)d_in[16];
    const float* att_W2 = (const float*)d_in[17];
    const float* att_b2 = (const float*)d_in[18];
    const float* cls_Wg = (const float*)d_in[19];
    const float* cls_bg = (const float*)d_in[20];
    const float* cls_W2 = (const float*)d_in[21];
    const float* cls_b2 = (const float*)d_in[22];

    char* wp = (char*)d_ws; size_t off = 0;
    auto alloc = [&](size_t bytes) -> void* {
        void* p = wp + off; off += (bytes + 255) & ~(size_t)255; return p;
    };
    // persistent
    u16*  tgt_e     = (u16*)alloc(4194304);     // [4096][512]
    u16*  enc_out   = (u16*)alloc(8388608);     // [64][64][1024]; _r contiguous
    u16*  enc_out_r = (u16*)alloc(8388608);
    u16*  WhhCat    = (u16*)alloc(4194304);     // [2][512][2048] (f,b; zmask=1)
    u16*  attW1     = (u16*)alloc(4718592);     // [1536][1536]
    u16*  clsWg     = (u16*)alloc(6815744);     // [3328][1024]
    float* bCatF    = (float*)alloc(16384);     // [2][2048] fp32
    float* h_f32    = (float*)alloc(524288);    // [4][64][512]; h,c,hbf contiguous
    float* c_f32    = (float*)alloc(524288);
    u16*  h_bf      = (u16*)alloc(262144);
    float* hg       = (float*)alloc(2097152);   // [4][64][2048]; reused dec gates
    float* dec_h    = (float*)alloc(131072);
    float* dec_c    = (float*)alloc(131072);
    u16*  dec_hbf   = (u16*)alloc(65536);
    float* hW1      = (float*)alloc(393216);    // [64][1536]
    float* scores   = (float*)alloc(32768);     // [2][4096]
    u16*  x_cat     = (u16*)alloc(393216);      // [64][3072]
    // overlaid regions (liveness-disjoint)
    char* R_AB  = (char*)alloc(8388608);        // src_e+rat_e -> Abuf
    char* R_Wih = (char*)alloc(4194304);        // WihCat -> Dbuf
    char* R_big = (char*)alloc(37748736);       // encW1+decWcat -> ci+hid
    char* R_xg  = (char*)alloc(67108864);       // xg -> clsW2

    u16* src_e  = (u16*)R_AB;                   // dead after xg GEMMs
    u16* rat_e  = (u16*)(R_AB + 4194304);
    u16* Abuf   = (u16*)R_AB;                   // [2][64][32][1024], decoder on
    u16* WihCat = (u16*)R_Wih;                  // [2][512][2048], dead after xg
    u16* Dbuf   = (u16*)R_Wih;                  // [64][32][512], decoder on
    u16* encW1  = (u16*)R_big;                  // [2][4096][1536], dead after dec
    u16* decWcat = (u16*)(R_big + 25165824);    // [3072][2048], dead after dec
    u16* ci     = (u16*)R_big;                  // [4096][3328], after dec
    u16* hid    = (u16*)(R_big + 27262976);     // [4096][1024]
    u16* xg     = (u16*)R_xg;                   // [4][4096][2048], encoder only
    u16* clsW2  = (u16*)R_xg;                   // [1024][32000], after encoder

    auto cvt = [&](const float* s, u16* d, int n) {
        cvt_f2b<<<dim3((n / 8 + 255) / 256), 256, 0, stream>>>(s, d, n / 8);
    };
    cvt(enc_Wih_f, WihCat,            1048576);
    cvt(enc_Wih_b, WihCat + 1048576,  1048576);
    cvt(enc_Whh_f, WhhCat,            1048576);
    cvt(enc_Whh_b, WhhCat + 1048576,  1048576);
    cvt(dec_Wih,   decWcat,           5242880);
    cvt(dec_Whh,   decWcat + 5242880, 1048576);
    cvt(att_W1,    attW1,             2359296);
    cvt(cls_Wg,    clsWg,             3408896);
    copy_f32<<<2, 256, 0, stream>>>((const float4*)enc_b_f, (float4*)bCatF, 512);
    copy_f32<<<2, 256, 0, stream>>>((const float4*)enc_b_b, (float4*)(bCatF + 2048), 512);
    zero16<<<320, 256, 0, stream>>>((uint4*)h_f32, 81920);  // h,c,hbf

    embed_kernel<<<dim3(4096, 3), 64, 0, stream>>>(
        source_data, target_data, rationales, src_emb, tgt_emb, src_e, rat_e, tgt_e);

    // xg = x @ Wih + b  (z: {src|rat}_f, {src|rat}_b)
    gemm_bf16<<<dim3(32, 64, 2), 256, 0, stream>>>(
        src_e, 0, 512, WihCat, 1048576, 2048, 1, xg, 8388608, 2048,
        bCatF, 2048, 512, 1);
    gemm_bf16<<<dim3(32, 64, 2), 256, 0, stream>>>(
        rat_e, 0, 512, WihCat, 1048576, 2048, 1, xg + (size_t)2 * 8388608,
        8388608, 2048, bCatF, 2048, 512, 1);

    // encoder scan: h@Whh (4-z batched) + cell
    for (int t = 0; t < 64; ++t) {
        gemm_bf16<<<dim3(32, 1, 4), 256, 0, stream>>>(
            h_bf, 32768, 512, WhhCat, 1048576, 2048, 1, hg, 131072, 2048,
            nullptr, 0, 512, 0);
        enc_cell<<<dim3(128, 4), 256, 0, stream>>>(
            hg, xg, h_f32, c_f32, h_bf, enc_out, enc_out_r, t);
    }

    cvt(cls_W2, clsW2, 32768000);   // xg dead now; clsW2 overlays it

    init_dec<<<128, 256, 0, stream>>>(h_f32, c_f32, h_bf, dec_h, dec_c, dec_hbf,
                                      x_cat, tgt_e);

    // encW1 = enc_out @ W1[0:1024] + b1 (both attention sources, z=2)
    gemm_bf16<<<dim3(24, 64, 2), 256, 0, stream>>>(
        enc_out, 4194304, 1024, attW1, 0, 1536, 0, encW1, 6291456, 1536,
        att_b1, 0, 1024, 1);

    // decoder scan
    for (int t = 0; t < 32; ++t) {
        gemm_bf16<<<dim3(24, 1, 1), 256, 0, stream>>>(
            dec_hbf, 0, 512, attW1 + 1572864, 0, 1536, 0,
            hW1, 0, 1536, nullptr, 0, 512, 0);
        score_kernel<<<2048, 256, 0, stream>>>(encW1, hW1, att_W2, att_b2, scores);
        attn_out<<<dim3(64, 2), 256, 0, stream>>>(scores, enc_out, x_cat, Abuf, t);
        gemm_bf16<<<dim3(32, 1, 1), 256, 0, stream>>>(
            x_cat, 0, 3072, decWcat, 0, 2048, 0, hg, 0, 2048,
            dec_b, 0, 3072, 0);
        dec_cell<<<128, 256, 0, stream>>>(hg, dec_h, dec_c, dec_hbf, x_cat, Dbuf,
                                          tgt_e, t);
    }

    // classifier: ci/hid overlay encW1/decWcat (both dead)
    build_ci<<<4096, 256, 0, stream>>>(tgt_e, Abuf, graph_embs, Dbuf, ci);
    gemm_bf16<<<dim3(16, 64, 1), 256, 0, stream>>>(
        ci, 0, 3328, clsWg, 0, 1024, 0, hid, 0, 1024, cls_bg, 0, 3328, 1 | 2);
    gemm_bf16<<<dim3(500, 64, 1), 256, 0, stream>>>(
        hid, 0, 1024, clsW2, 0, 32000, 0, d_out, 0, 32000, cls_b2, 0, 1024, 0);
}